// Round 8
// baseline (852.111 us; speedup 1.0000x reference)
//
#include <hip/hip_runtime.h>

#define BATCH 4
#define NN 2048
#define MM 2048
#define DIM 128
#define HID 128

typedef __bf16 bf16x8 __attribute__((ext_vector_type(8)));
typedef float f32x16 __attribute__((ext_vector_type(16)));
typedef float f32x4 __attribute__((ext_vector_type(4)));
typedef float f32x2 __attribute__((ext_vector_type(2)));
typedef unsigned short ushort_t;
typedef ushort_t ushort8 __attribute__((ext_vector_type(8)));
typedef unsigned int uint_t;

#define LOG2E 1.44269504088896340736f
#define LN2   0.69314718055994530942f

__device__ __forceinline__ ushort_t f2bf(float f) {
  uint_t u = __builtin_bit_cast(uint_t, f);
  u += 0x7fffu + ((u >> 16) & 1u);
  return (ushort_t)(u >> 16);
}
__device__ __forceinline__ float bflo(uint_t p) { return __builtin_bit_cast(float, p << 16); }
__device__ __forceinline__ float bfhi(uint_t p) { return __builtin_bit_cast(float, p & 0xffff0000u); }

// ---- pre-kernel: fp32 -> bf16 convert + TILE-MAJOR repack of source_val ----
// Lane-linear layout (round-6 verified): chunk t = ((b*64 + jt)*8 + ks)*64 + c
// with c == consuming LANE: half = c>>5, l5 = c&31; chunk holds
// S[b][jt*32+l5][ks*16+half*8 .. +8] as 8 bf16.
// Main-kernel B-fragment load for fixed (jt,ks) is lane*16B contiguous ->
// one 1KB fully-coalesced wave instruction straight from L2 (Sb is 512KB per
// batch = L2-resident; all 2048 blocks of a batch share it).
__global__ void cvt_repack(const float* __restrict__ src, ushort_t* __restrict__ dst) {
  int t = blockIdx.x * 256 + threadIdx.x;   // 131072 chunks
  int c    = t & 63;
  int ks   = (t >> 6) & 7;
  int jt   = (t >> 9) & 63;
  int b    = t >> 15;
  int half = c >> 5, l5 = c & 31;           // lane-linear: c == lane
  int j    = jt * 32 + l5;
  int d0   = ks * 16 + half * 8;
  const float* s = src + ((size_t)(b * MM + j)) * DIM + d0;
  float4 v0 = *reinterpret_cast<const float4*>(s);
  float4 v1 = *reinterpret_cast<const float4*>(s + 4);
  ushort8 u;
  u[0] = f2bf(v0.x); u[1] = f2bf(v0.y); u[2] = f2bf(v0.z); u[3] = f2bf(v0.w);
  u[4] = f2bf(v1.x); u[5] = f2bf(v1.y); u[6] = f2bf(v1.z); u[7] = f2bf(v1.w);
  *reinterpret_cast<ushort8*>(dst + (size_t)t * 8) = u;
}

// ---- pre-kernel: pack (b_in*log2e, w_out*ln2) as bf16 pair per h ----
__global__ void pbw_kernel(const float* __restrict__ b_in, const float* __restrict__ w_out,
                           uint_t* __restrict__ pbw) {
  int h = threadIdx.x;
  pbw[h] = (uint_t)f2bf(b_in[h] * LOG2E) | ((uint_t)f2bf(w_out[h] * LN2) << 16);
}

// ---------------- main kernel ----------------
// 8192 blocks = one (b,i); 4 waves; wave wv owns h-quarter [32wv,32wv+32).
// ROUND 8 — ZERO barriers in the K-loop:
//   r7 counters: VALUBusy 54.6 + MfmaUtil 28.5 = 83% -> ~17% pure stall, and
//   the only remaining block-sync is the per-jt __syncthreads (64/block).
//   Fix: drop LDS staging of B; read fragments DIRECTLY from global (L2-hot,
//   1KB coalesced per (jt,ks) wave-instr thanks to the lane-linear repack).
//   Pipeline per jt: MFMA chain (consumes B) -> issue next jt's 8 loads
//   (WAR-safe: in-order issue guarantees MFMAs read B before loads rewrite)
//   -> epilogue (~200cy VALU) hides the L2 latency; 3 waves/SIMD TLP on top.
//   Waves drift freely; ONE final barrier before the cross-wave reduction.
//   Registers: afr 32 + B 32 (single buffer) + c0/c1 32 + cinit 16 + w2 16
//   + misc ~= 148 < 168 budget of (256,3) (thrice-confirmed no-spill cap).
// Keeps (verified): part[4][MM] write-once private rows, lane-linear repack,
// cinit bias-fold into MFMA C-in, one-time w2 unpack, packed-fp32 epilogue.
__launch_bounds__(256, 3)
__global__ void hmlp_kernel(const float* __restrict__ Tg, const ushort_t* __restrict__ Sb,
                            const float* __restrict__ Wg, const uint_t* __restrict__ pbw,
                            const float* __restrict__ b_out_p, float* __restrict__ Og) {
  __shared__ float part[4][MM];   // 32 KB: per-h-quarter output-row partials
  const int tid  = threadIdx.x;
  const int lane = tid & 63;
  const int wv   = tid >> 6;
  const int half = lane >> 5;     // lane half (0/1)
  const int l5   = lane & 31;
  const int blk  = blockIdx.x;
  const int b    = blk >> 11;     // 2048 blocks per batch
  const int i    = blk & 2047;
  const int hb   = wv << 5;       // this wave's h-base (0/32/64/96)

  // one-time unpack: bias' -> MFMA C-in seed, w' -> packed float2 pairs
  // h_r = hb + (r&3) + 8*(r>>2) + 4*half  (C/D row map, verified)
  f32x16 cinit;
  f32x2 w2[8];
#pragma unroll
  for (int r = 0; r < 16; ++r) {
    uint_t pw = pbw[hb + (r & 3) + 8 * (r >> 2) + 4 * half];
    cinit[r] = bflo(pw);
    if (r & 1) w2[r >> 1].y = bfhi(pw); else w2[r >> 1].x = bfhi(pw);
  }

  // ---- A-fragments afr[ks] = bf16(LOG2E * t_i[d] * W[h][d]) ----
  // A row = hb + l5, k(=d) = ks*16 + half*8 + e   (verified)
  bf16x8 afr[8];
  {
    const float* tb = Tg + ((size_t)(b * NN + i)) * DIM;
    const float* wr = Wg + (size_t)(hb + l5) * DIM;
#pragma unroll
    for (int ks = 0; ks < 8; ++ks) {
      const int d0 = ks * 16 + half * 8;
      float4 w0 = *reinterpret_cast<const float4*>(wr + d0);
      float4 w1 = *reinterpret_cast<const float4*>(wr + d0 + 4);
      float4 t0 = *reinterpret_cast<const float4*>(tb + d0);
      float4 t1 = *reinterpret_cast<const float4*>(tb + d0 + 4);
      ushort8 u;
      u[0] = f2bf(w0.x * t0.x * LOG2E); u[1] = f2bf(w0.y * t0.y * LOG2E);
      u[2] = f2bf(w0.z * t0.z * LOG2E); u[3] = f2bf(w0.w * t0.w * LOG2E);
      u[4] = f2bf(w1.x * t1.x * LOG2E); u[5] = f2bf(w1.y * t1.y * LOG2E);
      u[6] = f2bf(w1.z * t1.z * LOG2E); u[7] = f2bf(w1.w * t1.w * LOG2E);
      afr[ks] = __builtin_bit_cast(bf16x8, u);
    }
  }

  // ---- B: direct from global (L2-hot), lane-linear tile-major layout ----
  const ushort_t* sbT = Sb + (size_t)b * (64 * 4096) + (size_t)lane * 8;

  auto loadB = [&](bf16x8 (&B)[8], int jt) {
    const ushort_t* p = sbT + (size_t)jt * 4096;
#pragma unroll
    for (int ks = 0; ks < 8; ++ks)
      B[ks] = *reinterpret_cast<const bf16x8*>(p + ks * 512);
  };

  bf16x8 B[8];
  loadB(B, 0);

#pragma unroll 1
  for (int jt = 0; jt < 64; ++jt) {
    // two independent 4-deep chains (ILP 2): k 0..63 / k 64..127
    f32x16 c0 = __builtin_amdgcn_mfma_f32_32x32x16_bf16(afr[0], B[0], cinit, 0, 0, 0);
    f32x16 c1 = __builtin_amdgcn_mfma_f32_32x32x16_bf16(afr[4], B[4], (f32x16)(0.f), 0, 0, 0);
#pragma unroll
    for (int ks = 1; ks < 4; ++ks) {
      c0 = __builtin_amdgcn_mfma_f32_32x32x16_bf16(afr[ks], B[ks], c0, 0, 0, 0);
      c1 = __builtin_amdgcn_mfma_f32_32x32x16_bf16(afr[ks + 4], B[ks + 4], c1, 0, 0, 0);
    }

    // B consumed by the (already-issued) MFMAs -> prefetch next tile into the
    // SAME registers (WAR-safe); the epilogue below covers the L2 latency.
    if (jt + 1 < 64) loadB(B, jt + 1);

    // epilogue (packed fp32): y log2-domain, p += w'*y*sigmoid; per pair:
    // 1 pk_add + 2 exp2 + 1 pk_add + 2 rcp + 1 pk_mul + 1 pk_fma
    f32x2 pc[4] = {f32x2{0.f, 0.f}, f32x2{0.f, 0.f}, f32x2{0.f, 0.f}, f32x2{0.f, 0.f}};
#define EPI_Q(q)                                                                     \
    {                                                                                \
      f32x2 y = __builtin_shufflevector(c0, c0, 2 * (q), 2 * (q) + 1)                \
              + __builtin_shufflevector(c1, c1, 2 * (q), 2 * (q) + 1);               \
      float e0 = __builtin_amdgcn_exp2f(-y.x);                                       \
      float e1 = __builtin_amdgcn_exp2f(-y.y);                                       \
      f32x2 d = f32x2{e0, e1} + 1.0f;                                                \
      f32x2 s = f32x2{__builtin_amdgcn_rcpf(d.x), __builtin_amdgcn_rcpf(d.y)};       \
      f32x2 ys = y * s;                                                              \
      pc[(q) & 3] = __builtin_elementwise_fma(w2[(q)], ys, pc[(q) & 3]);             \
    }
    EPI_Q(0) EPI_Q(1) EPI_Q(2) EPI_Q(3) EPI_Q(4) EPI_Q(5) EPI_Q(6) EPI_Q(7)
#undef EPI_Q
    f32x2 pv = (pc[0] + pc[1]) + (pc[2] + pc[3]);
    float p = pv.x + pv.y;
    p += __shfl_xor(p, 32, 64);                   // combine lane-halves' h-subsets
    if (lane < 32) part[wv][jt * 32 + l5] = p;    // write-once, private row
  }

  __syncthreads();   // the ONLY block-wide sync: part rows complete

  // final: sum 4 h-quarter rows + b_out; contiguous 1KB wave footprints
  {
    const float bo = b_out_p[0];
    const size_t ob = ((size_t)(b * NN + i)) * MM;
#pragma unroll
    for (int k = 0; k < 2; ++k) {
      const int j0 = k * 1024 + tid * 4;
      f32x4 v0 = *reinterpret_cast<const f32x4*>(&part[0][j0]);
      f32x4 v1 = *reinterpret_cast<const f32x4*>(&part[1][j0]);
      f32x4 v2 = *reinterpret_cast<const f32x4*>(&part[2][j0]);
      f32x4 v3 = *reinterpret_cast<const f32x4*>(&part[3][j0]);
      f32x4 o = (v0 + v1) + (v2 + v3);
      o[0] += bo; o[1] += bo; o[2] += bo; o[3] += bo;
      *reinterpret_cast<f32x4*>(&Og[ob + j0]) = o;
    }
  }
}

// ---------------- launch ----------------
extern "C" void kernel_launch(void* const* d_in, const int* in_sizes, int n_in,
                              void* d_out, int out_size, void* d_ws, size_t ws_size,
                              hipStream_t stream) {
  const float* Tg    = (const float*)d_in[0];
  const float* Sg    = (const float*)d_in[1];
  const float* Wg    = (const float*)d_in[2];
  const float* b_in  = (const float*)d_in[3];
  const float* W_out = (const float*)d_in[4];
  const float* b_out = (const float*)d_in[5];
  float* Og = (float*)d_out;

  ushort_t* Sb = (ushort_t*)d_ws;
  uint_t* pbw  = (uint_t*)((char*)d_ws + (size_t)BATCH * MM * DIM * 2);

  cvt_repack<<<(BATCH * MM * DIM) / (256 * 8), 256, 0, stream>>>(Sg, Sb);
  pbw_kernel<<<1, 128, 0, stream>>>(b_in, W_out, pbw);
  hmlp_kernel<<<BATCH * NN, 256, 0, stream>>>(Tg, Sb, Wg, pbw, b_out, Og);
}